// Round 1
// baseline (1629.234 us; speedup 1.0000x reference)
//
#include <hip/hip_runtime.h>
#include <hip/hip_bf16.h>
#include <math.h>

#define B_ 2
#define L_ 2048
#define D_ 1024
#define H_ 16
#define DH 64
#define ML (B_*L_)   // 4096

// ---------------------------------------------------------------------------
// 128x128x16 fp32 tiled GEMM:  C[M,N] = A[M,K] @ W[N,K]^T   (+ optional phi)
// mode 0: none; mode 1: phi(x) = elu(x)+1  (x>0 ? x+1 : exp(x))
// ---------------------------------------------------------------------------
__global__ __launch_bounds__(256)
void gemm_bt128(const float* __restrict__ A, const float* __restrict__ W,
                float* __restrict__ Cout, int M, int N, int K, int mode) {
    __shared__ float As[128][17];
    __shared__ float Bs[128][17];
    int tid = threadIdx.x;
    int tx = tid & 15, ty = tid >> 4;
    int m0 = blockIdx.x * 128, n0 = blockIdx.y * 128;

    float acc[8][8];
#pragma unroll
    for (int i = 0; i < 8; i++)
#pragma unroll
        for (int j = 0; j < 8; j++) acc[i][j] = 0.f;

    int lrow = tid >> 4;   // 0..15
    int lcol = tid & 15;   // 0..15

    for (int k0 = 0; k0 < K; k0 += 16) {
#pragma unroll
        for (int r = 0; r < 8; r++) {
            int row = lrow + 16 * r;
            As[row][lcol] = A[(size_t)(m0 + row) * K + k0 + lcol];
            Bs[row][lcol] = W[(size_t)(n0 + row) * K + k0 + lcol];
        }
        __syncthreads();
#pragma unroll
        for (int k = 0; k < 16; k++) {
            float a[8], b[8];
#pragma unroll
            for (int i = 0; i < 8; i++) a[i] = As[ty * 8 + i][k];
#pragma unroll
            for (int j = 0; j < 8; j++) b[j] = Bs[tx * 8 + j][k];
#pragma unroll
            for (int i = 0; i < 8; i++)
#pragma unroll
                for (int j = 0; j < 8; j++) acc[i][j] += a[i] * b[j];
        }
        __syncthreads();
    }

#pragma unroll
    for (int i = 0; i < 8; i++) {
        int row = m0 + ty * 8 + i;
#pragma unroll
        for (int j = 0; j < 8; j++) {
            int col = n0 + tx * 8 + j;
            float c = acc[i][j];
            if (mode == 1) c = (c > 0.f) ? (c + 1.f) : expf(c);
            Cout[(size_t)row * N + col] = c;
        }
    }
}

// ---------------------------------------------------------------------------
// Gate kernel: per (b,l) row compute 16 write-gates and 16 log-decay values.
// WG[(b*H+h)*L + l]   = sigmoid(x . Ww[h] + bw[h])
// GLOG[(b*H+h)*L + l] = log((1 - sigmoid(x . We[h] + be[h])) * 0.95 + 1e-8)
// ---------------------------------------------------------------------------
__global__ __launch_bounds__(64)
void gates_kernel(const float* __restrict__ x,
                  const float* __restrict__ Ww, const float* __restrict__ bw,
                  const float* __restrict__ We, const float* __restrict__ be,
                  float* __restrict__ WG, float* __restrict__ GLOG) {
    __shared__ float xs[D_];
    int row  = blockIdx.x;          // b*L + l
    int lane = threadIdx.x;
    const float* xr = x + (size_t)row * D_;
    for (int m = lane; m < D_; m += 64) xs[m] = xr[m];
    __syncthreads();
    int b = row / L_, l = row % L_;
    for (int h = 0; h < H_; ++h) {
        float sw = 0.f, se = 0.f;
        for (int m = lane; m < D_; m += 64) {
            float xv = xs[m];
            sw += xv * Ww[h * D_ + m];
            se += xv * We[h * D_ + m];
        }
#pragma unroll
        for (int off = 32; off > 0; off >>= 1) {
            sw += __shfl_xor(sw, off, 64);
            se += __shfl_xor(se, off, 64);
        }
        if (lane == 0) {
            float wgv = 1.f / (1.f + expf(-(sw + bw[h])));
            float egv = 1.f / (1.f + expf(-(se + be[h])));
            float g   = (1.f - egv) * 0.95f;
            size_t idx = ((size_t)(b * H_ + h)) * L_ + l;
            WG[idx]   = wgv;
            GLOG[idx] = logf(g + 1e-8f);
        }
    }
}

// ---------------------------------------------------------------------------
// Inclusive scan over L per (b,h): C = cumsum(GLOG). One wave per (b,h).
// ---------------------------------------------------------------------------
__global__ __launch_bounds__(64)
void scan_kernel(const float* __restrict__ GLOG, float* __restrict__ CC) {
    int bh = blockIdx.x;
    int lane = threadIdx.x;
    const float* src = GLOG + (size_t)bh * L_;
    float* dst = CC + (size_t)bh * L_;
    float running = 0.f;
    for (int base = 0; base < L_; base += 64) {
        float v = src[base + lane];
#pragma unroll
        for (int off = 1; off < 64; off <<= 1) {
            float u = __shfl_up(v, off, 64);
            if (lane >= off) v += u;
        }
        dst[base + lane] = running + v;
        running += __shfl(v, 63, 64);
    }
}

// ---------------------------------------------------------------------------
// Causal decayed linear-attention, 64x64 tiles, one (b,h,i-tile) per block.
// out_i = sum_{j<=i} (Q_i.K_j) wg_j exp(C_i - C_j) V_j / (denom_i + eps)
// ---------------------------------------------------------------------------
__global__ __launch_bounds__(256)
void attn_kernel(const float* __restrict__ Q, const float* __restrict__ K,
                 const float* __restrict__ V, const float* __restrict__ WG,
                 const float* __restrict__ CC, float* __restrict__ AO) {
    __shared__ float Qs[64][65];
    __shared__ float Ks[64][65];
    __shared__ float Vs[64][65];
    __shared__ float Es[64][65];
    __shared__ float Cis[64], Cjs[64], WGs[64];

    int bh = blockIdx.y; int b = bh >> 4; int h = bh & 15;
    int iT = blockIdx.x; int i0 = iT * 64;
    int t = threadIdx.x; int tx = t & 15; int ty = t >> 4;

    // load Q tile (64 rows x 64 dh), float4 per thread x4
    {
        int col4 = tx * 4;
#pragma unroll
        for (int r = 0; r < 4; r++) {
            int row = ty + r * 16;
            const float4 v = *(const float4*)(Q + ((size_t)(b * L_ + i0 + row)) * D_ + h * DH + col4);
            Qs[row][col4 + 0] = v.x; Qs[row][col4 + 1] = v.y;
            Qs[row][col4 + 2] = v.z; Qs[row][col4 + 3] = v.w;
        }
    }
    if (t < 64) Cis[t] = CC[(size_t)bh * L_ + i0 + t];

    float acc[4][4];
    float dpart[4];
#pragma unroll
    for (int i = 0; i < 4; i++) {
        dpart[i] = 0.f;
#pragma unroll
        for (int c = 0; c < 4; c++) acc[i][c] = 0.f;
    }

    for (int jt = 0; jt <= iT; ++jt) {
        int j0 = jt * 64;
        __syncthreads();   // protect Ks/Vs/Es from previous iteration's readers
        {
            int col4 = tx * 4;
#pragma unroll
            for (int r = 0; r < 4; r++) {
                int row = ty + r * 16;
                const float4 kv = *(const float4*)(K + ((size_t)(b * L_ + j0 + row)) * D_ + h * DH + col4);
                Ks[row][col4 + 0] = kv.x; Ks[row][col4 + 1] = kv.y;
                Ks[row][col4 + 2] = kv.z; Ks[row][col4 + 3] = kv.w;
                const float4 vv = *(const float4*)(V + ((size_t)(b * L_ + j0 + row)) * D_ + h * DH + col4);
                Vs[row][col4 + 0] = vv.x; Vs[row][col4 + 1] = vv.y;
                Vs[row][col4 + 2] = vv.z; Vs[row][col4 + 3] = vv.w;
            }
            if (t < 64) {
                Cjs[t] = CC[(size_t)bh * L_ + j0 + t];
                WGs[t] = WG[(size_t)bh * L_ + j0 + t];
            }
        }
        __syncthreads();

        // S = Q K^T on this tile (each thread a 4x4 micro-tile)
        float s[4][4];
#pragma unroll
        for (int i = 0; i < 4; i++)
#pragma unroll
            for (int j = 0; j < 4; j++) s[i][j] = 0.f;
        for (int k = 0; k < 64; k++) {
            float qa[4], kb[4];
#pragma unroll
            for (int i = 0; i < 4; i++) qa[i] = Qs[ty * 4 + i][k];
#pragma unroll
            for (int j = 0; j < 4; j++) kb[j] = Ks[tx * 4 + j][k];
#pragma unroll
            for (int i = 0; i < 4; i++)
#pragma unroll
                for (int j = 0; j < 4; j++) s[i][j] += qa[i] * kb[j];
        }

        bool diag = (jt == iT);
#pragma unroll
        for (int i = 0; i < 4; i++) {
            int gi = ty * 4 + i;
            float ci = Cis[gi];
#pragma unroll
            for (int j = 0; j < 4; j++) {
                int gj = tx * 4 + j;
                float e = 0.f;
                if (!diag || gj <= gi)
                    e = s[i][j] * WGs[gj] * expf(ci - Cjs[gj]);
                Es[gi][gj] = e;
                dpart[i] += e;
            }
        }
        __syncthreads();

        // acc[i][c] += sum_j Es[i][j] * Vs[j][c-range]
        for (int j = 0; j < 64; j++) {
            float vv[4], ev[4];
#pragma unroll
            for (int c = 0; c < 4; c++) vv[c] = Vs[j][tx * 4 + c];
#pragma unroll
            for (int i = 0; i < 4; i++) ev[i] = Es[ty * 4 + i][j];
#pragma unroll
            for (int i = 0; i < 4; i++)
#pragma unroll
                for (int c = 0; c < 4; c++) acc[i][c] += ev[i] * vv[c];
        }
    }

    // reduce denominators across the 16 threads sharing each row group (tx)
#pragma unroll
    for (int i = 0; i < 4; i++) {
        float d = dpart[i];
        d += __shfl_xor(d, 1, 16);
        d += __shfl_xor(d, 2, 16);
        d += __shfl_xor(d, 4, 16);
        d += __shfl_xor(d, 8, 16);
        dpart[i] = d;
    }

#pragma unroll
    for (int i = 0; i < 4; i++) {
        int gi = i0 + ty * 4 + i;
        float inv = 1.f / (dpart[i] + 1e-6f);
#pragma unroll
        for (int c = 0; c < 4; c++) {
            AO[((size_t)(b * L_ + gi)) * D_ + h * DH + tx * 4 + c] = acc[i][c] * inv;
        }
    }
}

// ---------------------------------------------------------------------------
extern "C" void kernel_launch(void* const* d_in, const int* in_sizes, int n_in,
                              void* d_out, int out_size, void* d_ws, size_t ws_size,
                              hipStream_t stream) {
    const float* x  = (const float*)d_in[0];
    const float* Wq = (const float*)d_in[1];
    const float* Wk = (const float*)d_in[2];
    const float* Wv = (const float*)d_in[3];
    const float* Wo = (const float*)d_in[4];
    const float* Ww = (const float*)d_in[5];
    const float* bw = (const float*)d_in[6];
    const float* We = (const float*)d_in[7];
    const float* be = (const float*)d_in[8];
    float* out = (float*)d_out;

    float* ws = (float*)d_ws;
    float* Q    = ws;                       // 4096*1024
    float* K    = ws + 4194304;
    float* V    = ws + 8388608;
    float* AO   = ws + 12582912;
    float* WG   = ws + 16777216;            // 2*16*2048
    float* GLOG = WG + 65536;
    float* CC   = GLOG + 65536;

    dim3 gproj(ML / 128, D_ / 128);         // 32 x 8
    gemm_bt128<<<gproj, 256, 0, stream>>>(x, Wq, Q, ML, D_, D_, 1);
    gemm_bt128<<<gproj, 256, 0, stream>>>(x, Wk, K, ML, D_, D_, 1);
    gemm_bt128<<<gproj, 256, 0, stream>>>(x, Wv, V, ML, D_, D_, 0);
    gates_kernel<<<ML, 64, 0, stream>>>(x, Ww, bw, We, be, WG, GLOG);
    scan_kernel<<<B_ * H_, 64, 0, stream>>>(GLOG, CC);
    attn_kernel<<<dim3(L_ / 64, B_ * H_), 256, 0, stream>>>(Q, K, V, WG, CC, AO);
    gemm_bt128<<<gproj, 256, 0, stream>>>(AO, Wo, out, ML, D_, D_, 0);
}

// Round 2
// 293.762 us; speedup vs baseline: 5.5461x; 5.5461x over previous
//
#include <hip/hip_runtime.h>
#include <hip/hip_bf16.h>
#include <math.h>

#define B_ 2
#define L_ 2048
#define D_ 1024
#define H_ 16
#define DH 64
#define ML (B_*L_)   // 4096

typedef __attribute__((ext_vector_type(8))) short bf16x8;
typedef __attribute__((ext_vector_type(4))) float f32x4;
typedef unsigned short u16;

__device__ __forceinline__ u16 f2bf(float f) {
    union { float f; unsigned u; } v; v.f = f;
    unsigned r = (v.u + 0x7FFFu + ((v.u >> 16) & 1u)) >> 16;
    return (u16)r;
}

// async global->LDS, 16B per lane. LDS dest must be linear base + lane*16.
__device__ __forceinline__ void async16(void* lds, const void* g) {
    __builtin_amdgcn_global_load_lds(
        (__attribute__((address_space(1))) unsigned int*)g,
        (__attribute__((address_space(3))) unsigned int*)lds,
        16, 0, 0);
}

// ---------------------------------------------------------------------------
// cast fp32 -> bf16 (vectorized)
// ---------------------------------------------------------------------------
__global__ __launch_bounds__(256)
void cast_f2b(const float* __restrict__ src, u16* __restrict__ dst, int n) {
    int i = (blockIdx.x * 256 + threadIdx.x) * 4;
    if (i + 3 < n) {
        float4 v = *(const float4*)(src + i);
        ushort4 o;
        o.x = f2bf(v.x); o.y = f2bf(v.y); o.z = f2bf(v.z); o.w = f2bf(v.w);
        *(ushort4*)(dst + i) = o;
    }
}

// ---------------------------------------------------------------------------
// bf16 MFMA GEMM: C[M,N] = A[M,K] @ W[N,K]^T
// 128x128 tile, BK=64, 4 waves (2x2), chunk-major LDS (conflict-free).
// mode 0: bf16 out; 1: phi + bf16 out; 2: f32 out
// ---------------------------------------------------------------------------
__global__ __launch_bounds__(256)
void gemm_mfma_bt(const u16* __restrict__ A, const u16* __restrict__ Bw,
                  void* __restrict__ Cout, int M, int N, int K, int mode) {
    __shared__ u16 As[8192];   // [8 cc][128 row][8]  (16KB)
    __shared__ u16 Bs[8192];
    int t = threadIdx.x, lane = t & 63;
    int w = t >> 6, wm = w >> 1, wn = w & 1;
    int l15 = lane & 15, l4 = lane >> 4;
    int m0 = blockIdx.x * 128, n0 = blockIdx.y * 128;

    f32x4 zz = {0.f, 0.f, 0.f, 0.f};
    f32x4 acc[4][4];
#pragma unroll
    for (int m = 0; m < 4; m++)
#pragma unroll
        for (int n = 0; n < 4; n++) acc[m][n] = zz;

    for (int k0 = 0; k0 < K; k0 += 64) {
#pragma unroll
        for (int i = 0; i < 4; i++) {
            int c = i * 256 + t;              // 0..1023
            int row = c & 127, cc = c >> 7;
            async16(&As[c * 8], A  + (size_t)(m0 + row) * K + k0 + cc * 8);
            async16(&Bs[c * 8], Bw + (size_t)(n0 + row) * K + k0 + cc * 8);
        }
        __syncthreads();   // drains vmcnt -> tiles ready

        bf16x8 af[4][2], bfr[4][2];
#pragma unroll
        for (int ks = 0; ks < 2; ks++) {
#pragma unroll
            for (int m = 0; m < 4; m++)
                af[m][ks] = *(const bf16x8*)&As[(l4 + 4 * ks) * 1024 + (wm * 64 + m * 16 + l15) * 8];
#pragma unroll
            for (int n = 0; n < 4; n++)
                bfr[n][ks] = *(const bf16x8*)&Bs[(l4 + 4 * ks) * 1024 + (wn * 64 + n * 16 + l15) * 8];
        }
#pragma unroll
        for (int m = 0; m < 4; m++)
#pragma unroll
            for (int n = 0; n < 4; n++) {
                acc[m][n] = __builtin_amdgcn_mfma_f32_16x16x32_bf16(af[m][0], bfr[n][0], acc[m][n], 0, 0, 0);
                acc[m][n] = __builtin_amdgcn_mfma_f32_16x16x32_bf16(af[m][1], bfr[n][1], acc[m][n], 0, 0, 0);
            }
        __syncthreads();   // done reading before next stage
    }

#pragma unroll
    for (int m = 0; m < 4; m++)
#pragma unroll
        for (int n = 0; n < 4; n++)
#pragma unroll
            for (int r = 0; r < 4; r++) {
                float c = acc[m][n][r];
                int row = m0 + wm * 64 + m * 16 + l4 * 4 + r;
                int col = n0 + wn * 64 + n * 16 + l15;
                if (mode == 1) c = (c > 0.f) ? (c + 1.f) : __expf(c);
                if (mode == 2) ((float*)Cout)[(size_t)row * N + col] = c;
                else           ((u16*)Cout)[(size_t)row * N + col] = f2bf(c);
            }
}

// ---------------------------------------------------------------------------
// Gates: per (b,l) row, 16 write-gates + 16 log-decay values  (fp32)
// ---------------------------------------------------------------------------
__global__ __launch_bounds__(64)
void gates_kernel(const float* __restrict__ x,
                  const float* __restrict__ Ww, const float* __restrict__ bw,
                  const float* __restrict__ We, const float* __restrict__ be,
                  float* __restrict__ WG, float* __restrict__ GLOG) {
    __shared__ float xs[D_];
    int row  = blockIdx.x;          // b*L + l
    int lane = threadIdx.x;
    const float* xr = x + (size_t)row * D_;
    for (int m = lane; m < D_; m += 64) xs[m] = xr[m];
    __syncthreads();
    int b = row / L_, l = row % L_;
    for (int h = 0; h < H_; ++h) {
        float sw = 0.f, se = 0.f;
        for (int m = lane; m < D_; m += 64) {
            float xv = xs[m];
            sw += xv * Ww[h * D_ + m];
            se += xv * We[h * D_ + m];
        }
#pragma unroll
        for (int off = 32; off > 0; off >>= 1) {
            sw += __shfl_xor(sw, off, 64);
            se += __shfl_xor(se, off, 64);
        }
        if (lane == 0) {
            float wgv = 1.f / (1.f + expf(-(sw + bw[h])));
            float egv = 1.f / (1.f + expf(-(se + be[h])));
            float g   = (1.f - egv) * 0.95f;
            size_t idx = ((size_t)(b * H_ + h)) * L_ + l;
            WG[idx]   = wgv;
            GLOG[idx] = logf(g + 1e-8f);
        }
    }
}

// ---------------------------------------------------------------------------
// Inclusive scan over L per (b,h)
// ---------------------------------------------------------------------------
__global__ __launch_bounds__(64)
void scan_kernel(const float* __restrict__ GLOG, float* __restrict__ CC) {
    int bh = blockIdx.x;
    int lane = threadIdx.x;
    const float* src = GLOG + (size_t)bh * L_;
    float* dst = CC + (size_t)bh * L_;
    float running = 0.f;
    for (int base = 0; base < L_; base += 64) {
        float v = src[base + lane];
#pragma unroll
        for (int off = 1; off < 64; off <<= 1) {
            float u = __shfl_up(v, off, 64);
            if (lane >= off) v += u;
        }
        dst[base + lane] = running + v;
        running += __shfl(v, 63, 64);
    }
}

// ---------------------------------------------------------------------------
// V transpose: Vb[ML][D] bf16 -> Vtb[B][H][DH][L] bf16
// ---------------------------------------------------------------------------
__global__ __launch_bounds__(256)
void transpose_v(const u16* __restrict__ Vb, u16* __restrict__ Vtb) {
    __shared__ u16 tile[64][72];
    int jt = blockIdx.x, bh = blockIdx.y;
    int b = bh >> 4, h = bh & 15;
    int j0 = jt * 64;
    int t = threadIdx.x;
    int row = t >> 2, ch = t & 3;
#pragma unroll
    for (int q = 0; q < 2; q++) {
        int cc = ch + q * 4;
        bf16x8 v = *(const bf16x8*)(Vb + (size_t)(b * L_ + j0 + row) * D_ + h * DH + cc * 8);
#pragma unroll
        for (int e = 0; e < 8; e++) tile[row][cc * 8 + e] = (u16)v[e];
    }
    __syncthreads();
#pragma unroll
    for (int q = 0; q < 2; q++) {
        int cc = (t & 3) + q * 4;
        int dh = t >> 2;
        bf16x8 o;
#pragma unroll
        for (int e = 0; e < 8; e++) o[e] = (short)tile[cc * 8 + e][dh];
        *(bf16x8*)(Vtb + (size_t)(bh * 64 + dh) * 2048 + j0 + cc * 8) = o;
    }
}

// ---------------------------------------------------------------------------
// MFMA attention. Block = (b,h,i-tile of 64 rows), 4 waves x 16 rows.
// Chunk-major LDS tiles: idx(row, cc) = cc*512 + row*8  (u16 units)
// ---------------------------------------------------------------------------
__device__ __forceinline__ void stage_tile_qk(u16* dstLds, const u16* src, int rowBase, int h) {
    int t = threadIdx.x, w = t >> 6, lane = t & 63;
#pragma unroll
    for (int i = 0; i < 2; i++) {
        int c = (w * 2 + i) * 64 + lane;     // 0..511
        int row = c & 63, cc = c >> 6;
        async16(&dstLds[c * 8], src + (size_t)(rowBase + row) * D_ + h * DH + cc * 8);
    }
}

__device__ __forceinline__ void stage_tile_vt(u16* dstLds, const u16* src, int bh, int j0) {
    int t = threadIdx.x, w = t >> 6, lane = t & 63;
#pragma unroll
    for (int i = 0; i < 2; i++) {
        int c = (w * 2 + i) * 64 + lane;
        int dh = c & 63, cc = c >> 6;
        async16(&dstLds[c * 8], src + (size_t)(bh * 64 + dh) * 2048 + j0 + cc * 8);
    }
}

__global__ __launch_bounds__(256)
void attn_mfma(const u16* __restrict__ Qb, const u16* __restrict__ Kb,
               const u16* __restrict__ Vtb, const float* __restrict__ WG,
               const float* __restrict__ CC, u16* __restrict__ AOb) {
    __shared__ u16 Qs[4096], Ks[4096], Vts[4096];
    __shared__ u16 Es[4096];    // per-wave 1024: [8 cc][16 row][8]
    int bh = blockIdx.y, b = bh >> 4, h = bh & 15;
    int iT = (int)(gridDim.x - 1) - (int)blockIdx.x;   // heavy blocks first
    int i0 = iT * 64;
    int t = threadIdx.x, w = t >> 6, lane = t & 63;
    int l15 = lane & 15, l4 = lane >> 4;
    int wrow = w * 16;

    stage_tile_qk(Qs, Qb, b * L_ + i0, h);
    stage_tile_qk(Ks, Kb, b * L_ + 0, h);
    stage_tile_vt(Vts, Vtb, bh, 0);
    __syncthreads();

    bf16x8 qa[2];
#pragma unroll
    for (int ks = 0; ks < 2; ks++)
        qa[ks] = *(const bf16x8*)&Qs[(l4 + 4 * ks) * 512 + (wrow + l15) * 8];
    float ci[4];
#pragma unroll
    for (int r = 0; r < 4; r++)
        ci[r] = CC[(size_t)bh * L_ + i0 + wrow + l4 * 4 + r];

    f32x4 zz = {0.f, 0.f, 0.f, 0.f};
    f32x4 acc[4];
#pragma unroll
    for (int n = 0; n < 4; n++) acc[n] = zz;
    float dsum[4] = {0.f, 0.f, 0.f, 0.f};

    for (int jt = 0; jt <= iT; ++jt) {
        int j0 = jt * 64;
        float cj[4], wg[4];
#pragma unroll
        for (int n = 0; n < 4; n++) {
            cj[n] = CC[(size_t)bh * L_ + j0 + n * 16 + l15];
            wg[n] = WG[(size_t)bh * L_ + j0 + n * 16 + l15];
        }

        // S = Q K^T  (wave's 16 rows x 64 cols)
        f32x4 s[4];
#pragma unroll
        for (int n = 0; n < 4; n++) s[n] = zz;
#pragma unroll
        for (int ks = 0; ks < 2; ks++) {
#pragma unroll
            for (int n = 0; n < 4; n++) {
                bf16x8 kb = *(const bf16x8*)&Ks[(l4 + 4 * ks) * 512 + (n * 16 + l15) * 8];
                s[n] = __builtin_amdgcn_mfma_f32_16x16x32_bf16(qa[ks], kb, s[n], 0, 0, 0);
            }
        }

        // decay * gate, denominator partials, E -> bf16 into per-wave LDS
        bool diag = (jt == iT);
#pragma unroll
        for (int n = 0; n < 4; n++) {
            int col = n * 16 + l15;
#pragma unroll
            for (int r = 0; r < 4; r++) {
                int rowl = l4 * 4 + r;
                float e = 0.f;
                if (!diag || col <= wrow + rowl)
                    e = s[n][r] * wg[n] * __expf(ci[r] - cj[n]);
                dsum[r] += e;
                Es[w * 1024 + (col >> 3) * 128 + rowl * 8 + (col & 7)] = f2bf(e);
            }
        }

        // PV: acc[n] += E(16x64) * V(64x64)
#pragma unroll
        for (int ks = 0; ks < 2; ks++) {
            bf16x8 ea = *(const bf16x8*)&Es[w * 1024 + (l4 + 4 * ks) * 128 + l15 * 8];
#pragma unroll
            for (int n = 0; n < 4; n++) {
                bf16x8 vb = *(const bf16x8*)&Vts[(l4 + 4 * ks) * 512 + (n * 16 + l15) * 8];
                acc[n] = __builtin_amdgcn_mfma_f32_16x16x32_bf16(ea, vb, acc[n], 0, 0, 0);
            }
        }

        if (jt < iT) {
            __syncthreads();                       // everyone done with K/Vt
            stage_tile_qk(Ks, Kb, b * L_ + j0 + 64, h);
            stage_tile_vt(Vts, Vtb, bh, j0 + 64);
            __syncthreads();                       // next tiles ready
        }
    }

    // denominator: sum across the 16-lane column group
#pragma unroll
    for (int r = 0; r < 4; r++) {
        float d = dsum[r];
        d += __shfl_xor(d, 1, 16);
        d += __shfl_xor(d, 2, 16);
        d += __shfl_xor(d, 4, 16);
        d += __shfl_xor(d, 8, 16);
        dsum[r] = d;
    }
#pragma unroll
    for (int n = 0; n < 4; n++)
#pragma unroll
        for (int r = 0; r < 4; r++) {
            float o = acc[n][r] / (dsum[r] + 1e-6f);
            AOb[(size_t)(b * L_ + i0 + wrow + l4 * 4 + r) * D_ + h * DH + n * 16 + l15] = f2bf(o);
        }
}

// ---------------------------------------------------------------------------
extern "C" void kernel_launch(void* const* d_in, const int* in_sizes, int n_in,
                              void* d_out, int out_size, void* d_ws, size_t ws_size,
                              hipStream_t stream) {
    const float* x  = (const float*)d_in[0];
    const float* Wq = (const float*)d_in[1];
    const float* Wk = (const float*)d_in[2];
    const float* Wv = (const float*)d_in[3];
    const float* Wo = (const float*)d_in[4];
    const float* Ww = (const float*)d_in[5];
    const float* bw = (const float*)d_in[6];
    const float* We = (const float*)d_in[7];
    const float* be = (const float*)d_in[8];
    float* out = (float*)d_out;

    char* wsb = (char*)d_ws;
    u16* xb  = (u16*)(wsb);                        // 8MB
    u16* Wqb = (u16*)(wsb + ((size_t)8  << 20));   // 2MB each
    u16* Wkb = (u16*)(wsb + ((size_t)10 << 20));
    u16* Wvb = (u16*)(wsb + ((size_t)12 << 20));
    u16* Wob = (u16*)(wsb + ((size_t)14 << 20));
    u16* Qb  = (u16*)(wsb + ((size_t)16 << 20));   // 8MB each
    u16* Kb  = (u16*)(wsb + ((size_t)24 << 20));
    u16* Vb  = (u16*)(wsb + ((size_t)32 << 20));
    u16* Vtb = (u16*)(wsb + ((size_t)40 << 20));
    u16* AOb = (u16*)(wsb + ((size_t)48 << 20));
    float* WG   = (float*)(wsb + ((size_t)56 << 20));
    float* GLOG = (float*)(wsb + ((size_t)56 << 20) + 262144);
    float* CC   = (float*)(wsb + ((size_t)56 << 20) + 524288);

    cast_f2b<<<4096, 256, 0, stream>>>(x,  xb,  ML * D_);
    cast_f2b<<<1024, 256, 0, stream>>>(Wq, Wqb, D_ * D_);
    cast_f2b<<<1024, 256, 0, stream>>>(Wk, Wkb, D_ * D_);
    cast_f2b<<<1024, 256, 0, stream>>>(Wv, Wvb, D_ * D_);
    cast_f2b<<<1024, 256, 0, stream>>>(Wo, Wob, D_ * D_);

    dim3 gp(ML / 128, D_ / 128);   // 32 x 8
    gemm_mfma_bt<<<gp, 256, 0, stream>>>(xb, Wqb, Qb, ML, D_, D_, 1);
    gemm_mfma_bt<<<gp, 256, 0, stream>>>(xb, Wkb, Kb, ML, D_, D_, 1);
    gemm_mfma_bt<<<gp, 256, 0, stream>>>(xb, Wvb, Vb, ML, D_, D_, 0);

    gates_kernel<<<ML, 64, 0, stream>>>(x, Ww, bw, We, be, WG, GLOG);
    scan_kernel<<<B_ * H_, 64, 0, stream>>>(GLOG, CC);
    transpose_v<<<dim3(L_ / 64, B_ * H_), 256, 0, stream>>>(Vb, Vtb);

    attn_mfma<<<dim3(L_ / 64, B_ * H_), 256, 0, stream>>>(Qb, Kb, Vtb, WG, CC, AOb);

    gemm_mfma_bt<<<gp, 256, 0, stream>>>(AOb, Wob, out, ML, D_, D_, 2);
}

// Round 3
// 241.646 us; speedup vs baseline: 6.7422x; 1.2157x over previous
//
#include <hip/hip_runtime.h>
#include <hip/hip_bf16.h>
#include <math.h>

#define B_ 2
#define L_ 2048
#define D_ 1024
#define H_ 16
#define DH 64
#define ML (B_*L_)      // 4096
#define QKV_N 3072

typedef __attribute__((ext_vector_type(8)))  short bf16x8;
typedef __attribute__((ext_vector_type(4)))  float f32x4;
typedef __attribute__((ext_vector_type(16))) float f32x16;
typedef unsigned short u16;

__device__ __forceinline__ u16 f2bf(float f) {
    union { float f; unsigned u; } v; v.f = f;
    unsigned r = (v.u + 0x7FFFu + ((v.u >> 16) & 1u)) >> 16;
    return (u16)r;
}

// async global->LDS, 16B per lane (lds dest must be linear base + lane*16).
__device__ __forceinline__ void async16(void* lds, const void* g) {
    __builtin_amdgcn_global_load_lds(
        (__attribute__((address_space(1))) unsigned int*)g,
        (__attribute__((address_space(3))) unsigned int*)lds,
        16, 0, 0);
}

// ---------------------------------------------------------------------------
// casts
// ---------------------------------------------------------------------------
__global__ __launch_bounds__(256)
void cast_f2b(const float* __restrict__ src, u16* __restrict__ dst, int n) {
    int i = (blockIdx.x * 256 + threadIdx.x) * 4;
    if (i + 3 < n) {
        float4 v = *(const float4*)(src + i);
        ushort4 o;
        o.x = f2bf(v.x); o.y = f2bf(v.y); o.z = f2bf(v.z); o.w = f2bf(v.w);
        *(ushort4*)(dst + i) = o;
    }
}

// pack Wq,Wk,Wv,Wo (each 1M elements) into Wcat bf16 [4096][1024]
__global__ __launch_bounds__(256)
void cast_w4(const float* __restrict__ Wq, const float* __restrict__ Wk,
             const float* __restrict__ Wv, const float* __restrict__ Wo,
             u16* __restrict__ dst) {
    int i = (blockIdx.x * 256 + threadIdx.x) * 4;     // 0..4M-1
    int sel = i >> 20;
    const float* s = sel == 0 ? Wq : sel == 1 ? Wk : sel == 2 ? Wv : Wo;
    float4 v = *(const float4*)(s + (i & 1048575));
    ushort4 o;
    o.x = f2bf(v.x); o.y = f2bf(v.y); o.z = f2bf(v.z); o.w = f2bf(v.w);
    *(ushort4*)(dst + i) = o;
}

// ---------------------------------------------------------------------------
// bf16 MFMA GEMM: C[M,N] = A[M,K] @ W[N,K]^T, 128x128 tile, BK=64, 4 waves.
// phi applied when global col < phiLimit. f32out selects output dtype.
// ---------------------------------------------------------------------------
__global__ __launch_bounds__(256)
void gemm_mfma_bt(const u16* __restrict__ A, const u16* __restrict__ Bw,
                  void* __restrict__ Cout, int M, int N, int K,
                  int phiLimit, int f32out) {
    __shared__ u16 As[8192];   // chunk-major [8 cc][128 row][8]
    __shared__ u16 Bs[8192];
    int t = threadIdx.x, lane = t & 63;
    int w = t >> 6, wm = w >> 1, wn = w & 1;
    int l15 = lane & 15, l4 = lane >> 4;
    int m0 = blockIdx.x * 128, n0 = blockIdx.y * 128;

    f32x4 zz = {0.f, 0.f, 0.f, 0.f};
    f32x4 acc[4][4];
#pragma unroll
    for (int m = 0; m < 4; m++)
#pragma unroll
        for (int n = 0; n < 4; n++) acc[m][n] = zz;

    for (int k0 = 0; k0 < K; k0 += 64) {
#pragma unroll
        for (int i = 0; i < 4; i++) {
            int c = i * 256 + t;
            int row = c & 127, cc = c >> 7;
            async16(&As[c * 8], A  + (size_t)(m0 + row) * K + k0 + cc * 8);
            async16(&Bs[c * 8], Bw + (size_t)(n0 + row) * K + k0 + cc * 8);
        }
        __syncthreads();

        bf16x8 af[4][2], bfr[4][2];
#pragma unroll
        for (int ks = 0; ks < 2; ks++) {
#pragma unroll
            for (int m = 0; m < 4; m++)
                af[m][ks] = *(const bf16x8*)&As[(l4 + 4 * ks) * 1024 + (wm * 64 + m * 16 + l15) * 8];
#pragma unroll
            for (int n = 0; n < 4; n++)
                bfr[n][ks] = *(const bf16x8*)&Bs[(l4 + 4 * ks) * 1024 + (wn * 64 + n * 16 + l15) * 8];
        }
#pragma unroll
        for (int m = 0; m < 4; m++)
#pragma unroll
            for (int n = 0; n < 4; n++) {
                acc[m][n] = __builtin_amdgcn_mfma_f32_16x16x32_bf16(af[m][0], bfr[n][0], acc[m][n], 0, 0, 0);
                acc[m][n] = __builtin_amdgcn_mfma_f32_16x16x32_bf16(af[m][1], bfr[n][1], acc[m][n], 0, 0, 0);
            }
        __syncthreads();
    }

#pragma unroll
    for (int m = 0; m < 4; m++)
#pragma unroll
        for (int n = 0; n < 4; n++)
#pragma unroll
            for (int r = 0; r < 4; r++) {
                float c = acc[m][n][r];
                int row = m0 + wm * 64 + m * 16 + l4 * 4 + r;
                int col = n0 + wn * 64 + n * 16 + l15;
                if (col < phiLimit) c = (c > 0.f) ? (c + 1.f) : __expf(c);
                if (f32out) ((float*)Cout)[(size_t)row * N + col] = c;
                else        ((u16*)Cout)[(size_t)row * N + col] = f2bf(c);
            }
}

// ---------------------------------------------------------------------------
// Gates (fp32): block = 16 rows x 32 gates. Outputs log-domain:
// LWG  = log(sigmoid(x.Ww + bw))
// GLOG = log((1 - sigmoid(x.We + be)) * 0.95 + 1e-8)
// ---------------------------------------------------------------------------
__global__ __launch_bounds__(256)
void gates_kernel(const float* __restrict__ x,
                  const float* __restrict__ Ww, const float* __restrict__ bw,
                  const float* __restrict__ We, const float* __restrict__ be,
                  float* __restrict__ GLOG, float* __restrict__ LWG) {
    __shared__ float xs[16][132];
    __shared__ float ws[32][132];
    int r0 = blockIdx.x * 16;
    int t = threadIdx.x;
    int r = t >> 4, h = t & 15;
    float sw = 0.f, se = 0.f;
    for (int k0 = 0; k0 < D_; k0 += 128) {
#pragma unroll
        for (int i = 0; i < 2; i++) {
            int c = (i * 256 + t) * 4;
            int rr = c >> 7, kk = c & 127;
            *(float4*)&xs[rr][kk] = *(const float4*)&x[(size_t)(r0 + rr) * D_ + k0 + kk];
        }
#pragma unroll
        for (int i = 0; i < 4; i++) {
            int c = (i * 256 + t) * 4;
            int rr = c >> 7, kk = c & 127;
            const float* src = rr < 16 ? &Ww[(size_t)rr * D_ + k0 + kk]
                                       : &We[(size_t)(rr - 16) * D_ + k0 + kk];
            *(float4*)&ws[rr][kk] = *(const float4*)src;
        }
        __syncthreads();
#pragma unroll
        for (int kk = 0; kk < 128; kk += 4) {
            float4 xv = *(const float4*)&xs[r][kk];
            float4 w1 = *(const float4*)&ws[h][kk];
            float4 w2 = *(const float4*)&ws[16 + h][kk];
            sw += xv.x * w1.x + xv.y * w1.y + xv.z * w1.z + xv.w * w1.w;
            se += xv.x * w2.x + xv.y * w2.y + xv.z * w2.z + xv.w * w2.w;
        }
        __syncthreads();
    }
    int row = r0 + r; int b = row >> 11, l = row & 2047;
    float wgv = 1.f / (1.f + __expf(-(sw + bw[h])));
    float egv = 1.f / (1.f + __expf(-(se + be[h])));
    size_t idx = ((size_t)(b * H_ + h)) * L_ + l;
    LWG[idx]  = __logf(wgv);
    GLOG[idx] = __logf((1.f - egv) * 0.95f + 1e-8f);
}

// ---------------------------------------------------------------------------
// Inclusive scan per (b,h): CC = cumsum(GLOG); CJW = CC - LWG
// ---------------------------------------------------------------------------
__global__ __launch_bounds__(64)
void scan_kernel(const float* __restrict__ GLOG, const float* __restrict__ LWG,
                 float* __restrict__ CC, float* __restrict__ CJW) {
    int bh = blockIdx.x;
    int lane = threadIdx.x;
    const float* src = GLOG + (size_t)bh * L_;
    const float* lw  = LWG  + (size_t)bh * L_;
    float* dst  = CC  + (size_t)bh * L_;
    float* dstw = CJW + (size_t)bh * L_;
    float running = 0.f;
    for (int base = 0; base < L_; base += 64) {
        float v = src[base + lane];
#pragma unroll
        for (int off = 1; off < 64; off <<= 1) {
            float u = __shfl_up(v, off, 64);
            if (lane >= off) v += u;
        }
        float c = running + v;
        dst[base + lane]  = c;
        dstw[base + lane] = c - lw[base + lane];
        running += __shfl(v, 63, 64);
    }
}

// ---------------------------------------------------------------------------
// V transpose: QKV V-cols -> Vtb[B*H*64 dh rows][2048 j]
// ---------------------------------------------------------------------------
__global__ __launch_bounds__(256)
void transpose_v(const u16* __restrict__ Vq, u16* __restrict__ Vtb) {
    __shared__ u16 tile[64][72];
    int jt = blockIdx.x, bh = blockIdx.y;
    int b = bh >> 4, h = bh & 15;
    int j0 = jt * 64;
    int t = threadIdx.x;
    int row = t >> 2;
#pragma unroll
    for (int q = 0; q < 2; q++) {
        int cc = (t & 3) + q * 4;
        bf16x8 v = *(const bf16x8*)(Vq + (size_t)(b * L_ + j0 + row) * QKV_N + h * DH + cc * 8);
#pragma unroll
        for (int e = 0; e < 8; e++) tile[row][cc * 8 + e] = (u16)v[e];
    }
    __syncthreads();
#pragma unroll
    for (int q = 0; q < 2; q++) {
        int cc = (t & 3) + q * 4;
        int dh = t >> 2;
        bf16x8 o;
#pragma unroll
        for (int e = 0; e < 8; e++) o[e] = (short)tile[cc * 8 + e][dh];
        *(bf16x8*)(Vtb + (size_t)(bh * 64 + dh) * 2048 + j0 + cc * 8) = o;
    }
}

// ---------------------------------------------------------------------------
// Attention: swapped-QK 32x32x16 MFMA, in-register E, dbuf K/V staging.
// Block = (b,h,i-tile 64), 2 waves x 32 rows. Lane: l31 = Q-row, hi = l>>5.
// ---------------------------------------------------------------------------
__global__ __launch_bounds__(128, 2)
void attn_mfma(const u16* __restrict__ QKV, const u16* __restrict__ Vtb,
               const float* __restrict__ CCg, const float* __restrict__ CJWg,
               u16* __restrict__ AOb) {
    __shared__ u16 Ks[2][4096];     // chunk-major [8 cc][64 row][8]
    __shared__ u16 Vs[2][4096];     // chunk-major [8 cc][64 dh][8]
    __shared__ float cjws[2048];

    int bh = blockIdx.y, b = bh >> 4, h = bh & 15;
    int xx = blockIdx.x;
    int iT = (xx & 1) ? (xx >> 1) : (31 - (xx >> 1));   // heavy/light interleave
    int i0 = iT * 64;
    int t = threadIdx.x, w = t >> 6, lane = t & 63;
    int l31 = lane & 31, hi = lane >> 5;
    int w32 = w * 32;

    // stage CJW for this (b,h) once
#pragma unroll
    for (int rnd = 0; rnd < 4; rnd++) {
        int c = rnd * 128 + t;
        async16(&cjws[c * 4], CJWg + (size_t)bh * L_ + c * 4);
    }

    // Q fragments + ci straight from global (once per block)
    const u16* qbase = QKV + (size_t)(b * L_ + i0 + w32 + l31) * QKV_N + h * DH;
    bf16x8 qb[4];
#pragma unroll
    for (int ks = 0; ks < 4; ks++)
        qb[ks] = *(const bf16x8*)(qbase + ks * 16 + hi * 8);
    float ci = CCg[(size_t)bh * L_ + i0 + w32 + l31];

    auto STAGE = [&](int buf, int jt) {
        int j0s = jt * 64;
        const u16* kbg = QKV + 1024 + (size_t)(b * L_ + j0s) * QKV_N + h * DH;
#pragma unroll
        for (int rnd = 0; rnd < 4; rnd++) {
            int c = rnd * 128 + t;
            int row = c & 63, cc = c >> 6;
            async16(&Ks[buf][c * 8], kbg + (size_t)row * QKV_N + cc * 8);
        }
        const u16* vbg = Vtb + (size_t)(bh * 64) * 2048 + j0s;
#pragma unroll
        for (int rnd = 0; rnd < 4; rnd++) {
            int c = rnd * 128 + t;
            int dh = c & 63, cc = c >> 6;
            async16(&Vs[buf][c * 8], vbg + (size_t)dh * 2048 + cc * 8);
        }
    };

    f32x16 z16;
#pragma unroll
    for (int r = 0; r < 16; r++) z16[r] = 0.f;
    f32x16 acc[2];
    acc[0] = z16; acc[1] = z16;
    float dloc = 0.f;

    STAGE(0, 0);
    __syncthreads();   // drains vmcnt + lgkm: tile 0 + cjw ready

    int cur = 0;
    for (int jt = 0; jt <= iT; ++jt) {
        int j0 = jt * 64;
        if (jt < iT) STAGE(cur ^ 1, jt + 1);
        bool diag = (jt == iT);

        // ---- QK^T swapped: st[n] = S^T frag, S[j][i], i = l31 ----
        f32x16 st[2];
        st[0] = z16; st[1] = z16;
#pragma unroll
        for (int ks = 0; ks < 4; ks++) {
            bf16x8 k0 = *(const bf16x8*)&Ks[cur][((ks * 2 + hi) * 64 + l31) * 8];
            bf16x8 k1 = *(const bf16x8*)&Ks[cur][((ks * 2 + hi) * 64 + 32 + l31) * 8];
            st[0] = __builtin_amdgcn_mfma_f32_32x32x16_bf16(k0, qb[ks], st[0], 0, 0, 0);
            st[1] = __builtin_amdgcn_mfma_f32_32x32x16_bf16(k1, qb[ks], st[1], 0, 0, 0);
        }

        // ---- decay/gate/mask in-register, pack to bf16 quads ----
        unsigned pk[2][4][2];
#pragma unroll
        for (int n = 0; n < 2; n++) {
#pragma unroll
            for (int rq = 0; rq < 4; rq++) {
                float4 cj4 = *(const float4*)&cjws[j0 + n * 32 + rq * 8 + hi * 4];
                float e0, e1, e2, e3;
                {
                    float a;
                    a = fminf(ci - cj4.x, 0.f); e0 = st[n][rq * 4 + 0] * __expf(a);
                    a = fminf(ci - cj4.y, 0.f); e1 = st[n][rq * 4 + 1] * __expf(a);
                    a = fminf(ci - cj4.z, 0.f); e2 = st[n][rq * 4 + 2] * __expf(a);
                    a = fminf(ci - cj4.w, 0.f); e3 = st[n][rq * 4 + 3] * __expf(a);
                }
                if (diag) {
                    int jb = n * 32 + rq * 8 + hi * 4;
                    int lim = w32 + l31;
                    e0 = (jb + 0 <= lim) ? e0 : 0.f;
                    e1 = (jb + 1 <= lim) ? e1 : 0.f;
                    e2 = (jb + 2 <= lim) ? e2 : 0.f;
                    e3 = (jb + 3 <= lim) ? e3 : 0.f;
                }
                dloc += (e0 + e1) + (e2 + e3);
                asm("v_cvt_pk_bf16_f32 %0, %1, %2" : "=v"(pk[n][rq][0]) : "v"(e0), "v"(e1));
                asm("v_cvt_pk_bf16_f32 %0, %1, %2" : "=v"(pk[n][rq][1]) : "v"(e2), "v"(e3));
            }
        }

        // ---- exchange halves across hi (lane ^ 32) ----
        unsigned rcv[2][4][2];
#pragma unroll
        for (int n = 0; n < 2; n++)
#pragma unroll
            for (int q = 0; q < 4; q++)
#pragma unroll
                for (int u = 0; u < 2; u++)
                    rcv[n][q][u] = (unsigned)__shfl_xor((int)pk[n][q][u], 32, 64);

        // ---- assemble PV A-frags and multiply against V ----
#pragma unroll
        for (int wi = 0; wi < 4; wi++) {
            int n = wi >> 1, qA = 2 * (wi & 1), qB = qA + 1;
            union { unsigned u[4]; bf16x8 v; } aw;
            aw.u[0] = hi ? rcv[n][qB][0] : pk[n][qA][0];
            aw.u[1] = hi ? rcv[n][qB][1] : pk[n][qA][1];
            aw.u[2] = hi ? pk[n][qB][0] : rcv[n][qA][0];
            aw.u[3] = hi ? pk[n][qB][1] : rcv[n][qA][1];
#pragma unroll
            for (int m = 0; m < 2; m++) {
                bf16x8 vb = *(const bf16x8*)&Vs[cur][((wi * 2 + hi) * 64 + m * 32 + l31) * 8];
                acc[m] = __builtin_amdgcn_mfma_f32_32x32x16_bf16(aw.v, vb, acc[m], 0, 0, 0);
            }
        }

        __syncthreads();   // drains vmcnt(0): next tile staged, reads done
        cur ^= 1;
    }

    // denominator: other hi-half holds the rest of row i = l31
    float dtot = dloc + __shfl_xor(dloc, 32, 64);

#pragma unroll
    for (int m = 0; m < 2; m++)
#pragma unroll
        for (int r = 0; r < 16; r++) {
            int il = (r & 3) + 8 * (r >> 2) + 4 * hi;
            float d = __shfl(dtot, il, 64);
            float o = acc[m][r] / (d + 1e-6f);
            int ig = i0 + w32 + il;
            AOb[(size_t)(b * L_ + ig) * D_ + h * DH + m * 32 + l31] = f2bf(o);
        }
}

// ---------------------------------------------------------------------------
extern "C" void kernel_launch(void* const* d_in, const int* in_sizes, int n_in,
                              void* d_out, int out_size, void* d_ws, size_t ws_size,
                              hipStream_t stream) {
    const float* x  = (const float*)d_in[0];
    const float* Wq = (const float*)d_in[1];
    const float* Wk = (const float*)d_in[2];
    const float* Wv = (const float*)d_in[3];
    const float* Wo = (const float*)d_in[4];
    const float* Ww = (const float*)d_in[5];
    const float* bw = (const float*)d_in[6];
    const float* We = (const float*)d_in[7];
    const float* be = (const float*)d_in[8];
    float* out = (float*)d_out;

    char* wsb = (char*)d_ws;
    u16* xb   = (u16*)(wsb);                        // 8MB
    u16* Wcat = (u16*)(wsb + ((size_t)8  << 20));   // 8MB  [Wq;Wk;Wv;Wo] bf16
    u16* QKV  = (u16*)(wsb + ((size_t)16 << 20));   // 24MB [4096][3072]
    u16* Vtb  = (u16*)(wsb + ((size_t)40 << 20));   // 8MB  [B*H*64][2048]
    u16* AOb  = (u16*)(wsb + ((size_t)48 << 20));   // 8MB  [4096][1024]
    float* GLOG = (float*)(wsb + ((size_t)56 << 20));
    float* LWG  = GLOG + 65536;
    float* CC   = LWG  + 65536;
    float* CJW  = CC   + 65536;

    cast_f2b<<<4096, 256, 0, stream>>>(x, xb, ML * D_);
    cast_w4<<<4096, 256, 0, stream>>>(Wq, Wk, Wv, Wo, Wcat);

    // fused Q,K,V projection: N = 3072, phi on cols < 2048 (Q,K)
    gemm_mfma_bt<<<dim3(ML / 128, QKV_N / 128), 256, 0, stream>>>(
        xb, Wcat, QKV, ML, QKV_N, D_, 2048, 0);

    gates_kernel<<<ML / 16, 256, 0, stream>>>(x, Ww, bw, We, be, GLOG, LWG);
    scan_kernel<<<B_ * H_, 64, 0, stream>>>(GLOG, LWG, CC, CJW);
    transpose_v<<<dim3(L_ / 64, B_ * H_), 256, 0, stream>>>(QKV + 2048, Vtb);

    attn_mfma<<<dim3(L_ / 64, B_ * H_), 128, 0, stream>>>(QKV, Vtb, CC, CJW, AOb);

    gemm_mfma_bt<<<dim3(ML / 128, D_ / 128), 256, 0, stream>>>(
        AOb, Wcat + (size_t)3072 * 1024, out, ML, D_, D_, 0, 1);
}